// Round 7
// baseline (1446.789 us; speedup 1.0000x reference)
//
#include <hip/hip_runtime.h>

// Round 7: k_pab latency fix. h-row loads moved from scalar pipe (SMEM is
// out-of-order on lgkmcnt -> per-node drain stall) to vector pipe via a
// VGPR-pinned pointer: same-address-per-lane broadcast loads, vmcnt-ordered,
// so the compiler pipelines next-node loads under current-node FMAs.
// Everything else identical to round 6.

#define E 64
#define TWO_E 128

__device__ __forceinline__ void sfma32(float (&acc)[32], float xu, const float* w) {
  #pragma unroll
  for (int i = 0; i < 32; ++i) acc[i] = fmaf(xu, w[i], acc[i]);
}

__device__ __forceinline__ const float* vpin(const float* p) {
  unsigned long long u = (unsigned long long)p;
  asm("" : "+v"(u));          // force VGPR address -> global_load (vmcnt, in-order)
  return (const float*)u;
}

// ---------------- zero ----------------
__global__ void k_zero(float4* __restrict__ p, int n4) {
  int i = blockIdx.x * blockDim.x + threadIdx.x;
  if (i < n4) p[i] = make_float4(0.f, 0.f, 0.f, 0.f);
}

// ---------------- CSR build (once per launch; edge slots only) ----------------
__global__ void k_count_e(const int* __restrict__ rel_e, int* __restrict__ cnt,
                          int* __restrict__ cpos0, int* __restrict__ cpos1, int M2) {
  int q = blockIdx.x * blockDim.x + threadIdx.x;
  if (q >= M2) return;
  int n = rel_e[q];
  atomicAdd(&cnt[n], 1);
  atomicAdd(&((q & 1) ? cpos1 : cpos0)[n], 1);
}
__global__ void k_count_u(const int* __restrict__ rel_u, int* __restrict__ cnt_u, int mu) {
  int m = blockIdx.x * blockDim.x + threadIdx.x;
  if (m >= mu) return;
  atomicAdd(&cnt_u[rel_u[m]], 1);
}

__global__ void __launch_bounds__(1024) k_scan(const int* __restrict__ cnt,
                                               int* __restrict__ startp, int nn, int M2) {
  __shared__ int ls[1024];
  int t = threadIdx.x;
  const int C = 49;                        // 49*1024 >= 50000
  int c0 = t * C, c1 = min(c0 + C, nn);
  int s = 0;
  for (int i = c0; i < c1; ++i) s += cnt[i];
  ls[t] = s;
  __syncthreads();
  for (int off = 1; off < 1024; off <<= 1) {
    int v = (t >= off) ? ls[t - off] : 0;
    __syncthreads();
    ls[t] += v;
    __syncthreads();
  }
  int run = (t > 0) ? ls[t - 1] : 0;
  for (int i = c0; i < c1; ++i) { startp[i] = run; run += cnt[i]; }
  if (t == 1023) startp[nn] = M2;
}

__global__ void k_copyint(const int* __restrict__ a, int* __restrict__ b, int n) {
  int i = blockIdx.x * blockDim.x + threadIdx.x;
  if (i < n) b[i] = a[i];
}

__global__ void k_fill_e(const int* __restrict__ rel_e, int* __restrict__ cursor,
                         int* __restrict__ idx, int M2) {
  int q = blockIdx.x * blockDim.x + threadIdx.x;
  if (q >= M2) return;
  int p = atomicAdd(&cursor[rel_e[q]], 1);
  idx[p] = q;
}

// ------- mu0 = MLP_u(0), me0 = MLP_e(0); also g(layer0) = br for all graphs ----
__global__ void k_mlp0(const float* __restrict__ b1u, const float* __restrict__ W2u,
                       const float* __restrict__ b2u,
                       const float* __restrict__ b1e, const float* __restrict__ W2e,
                       const float* __restrict__ b2e,
                       const float* __restrict__ br,
                       float* __restrict__ mu0, float* __restrict__ me0,
                       float* __restrict__ g, int gn) {
  __shared__ float hu[64], he[128];
  int t = threadIdx.x;                     // 128 threads
  if (t < 64) hu[t] = fmaxf(b1u[t], 0.f);
  he[t] = fmaxf(b1e[t], 0.f);
  __syncthreads();
  if (t < 64) {
    float a = b2u[t];
    for (int k = 0; k < 64; ++k) a = fmaf(hu[k], W2u[k * 64 + t], a);
    mu0[t] = a;
  }
  float a = b2e[t];
  for (int k = 0; k < 128; ++k) a = fmaf(he[k], W2e[k * TWO_E + t], a);
  me0[t] = a;
  if (t < 64) {
    float b = br[t];
    for (int gi = 0; gi < gn; ++gi) g[gi * 64 + t] = b;
  }
}

// ------- layer-0 agg from counts ----------
__global__ void k_agg0(const int* __restrict__ cnt_u, const int* __restrict__ cpos0,
                       const int* __restrict__ cpos1, const float* __restrict__ mu0,
                       const float* __restrict__ me0, float* __restrict__ agg, int nn) {
  int i = blockIdx.x * blockDim.x + threadIdx.x;   // (n, j4)
  int n = i >> 4, j4 = i & 15;
  if (n >= nn) return;
  float cu = (float)cnt_u[n], c0 = (float)cpos0[n], c1 = (float)cpos1[n];
  float4 m = ((const float4*)mu0)[j4];
  float4 a = ((const float4*)me0)[j4];
  float4 b = ((const float4*)(me0 + 64))[j4];
  ((float4*)agg)[i] = make_float4(cu * m.x + c0 * a.x + c1 * b.x,
                                  cu * m.y + c0 * a.y + c1 * b.y,
                                  cu * m.z + c0 * a.z + c1 * b.z,
                                  cu * m.w + c0 * a.w + c1 * b.w);
}

// ---------------- Pab[n] = [h[n]@W1_top + b1 | h[n]@W1_bot] ----------------
// lane = out col, wave wq owns 64-col chunk; W column slice in VGPRs;
// h rows loaded via vector-broadcast (vmcnt-ordered -> pipelined across nodes);
// stores coalesced 256 B per node.
__global__ void __launch_bounds__(256) k_pab(
    const float* __restrict__ h, const float* __restrict__ W1,  // [128][128]
    const float* __restrict__ b1, float* __restrict__ Pab, int nn)
{
  const int lane = threadIdx.x & 63;
  const int wq = __builtin_amdgcn_readfirstlane(threadIdx.x >> 6);  // 0..3
  const int c0 = wq * 64;                        // out col chunk in [0,256)
  const int rbase = (c0 < 128) ? 0 : 64;
  const int cw = (c0 < 128) ? c0 : (c0 - 128);
  const float badd = (c0 < 128) ? b1[cw + lane] : 0.f;   // fold b1 into Pa
  const int nb = blockIdx.x * 64;
  const int nend = (nn - nb < 64) ? (nn - nb) : 64;

  float wcol[64];
  #pragma unroll
  for (int k = 0; k < 64; ++k)
    wcol[k] = W1[(rbase + k) * TWO_E + cw + lane];

  #pragma unroll 2
  for (int ni = 0; ni < nend; ++ni) {
    int node = nb + ni;
    const float4* hv = (const float4*)vpin(h + (size_t)node * E);
    float a0 = 0.f, a1 = 0.f, a2 = 0.f, a3 = 0.f;
    #pragma unroll
    for (int k4 = 0; k4 < 16; ++k4) {
      float4 xv = hv[k4];
      a0 = fmaf(xv.x, wcol[4 * k4 + 0], a0);
      a1 = fmaf(xv.y, wcol[4 * k4 + 1], a1);
      a2 = fmaf(xv.z, wcol[4 * k4 + 2], a2);
      a3 = fmaf(xv.w, wcol[4 * k4 + 3], a3);
    }
    Pab[(size_t)node * 256 + c0 + lane] = (a0 + a1) + (a2 + a3) + badd;
  }
}

// ------- unary agg init: agg[n] = cnt_u[n] * MLP_u(h[n]) ----------
__global__ void __launch_bounds__(256) k_umsg_agg(
    const float* __restrict__ h, const int* __restrict__ cnt_u,
    const float* __restrict__ W1, const float* __restrict__ b1,
    const float* __restrict__ W2, const float* __restrict__ b2,
    float* __restrict__ agg, int nn)
{
  __shared__ __align__(16) float tl[128 * 68];
  const int tid = threadIdx.x;
  const int lane = tid & 63;
  const int wq = __builtin_amdgcn_readfirstlane(tid >> 6);
  const int g = wq >> 1, q = wq & 1;
  const int n = blockIdx.x * 128 + g * 64 + lane;
  const bool valid = (n < nn);
  const int nc = valid ? n : (nn - 1);
  const float4* x4 = (const float4*)(h + (size_t)nc * E);
  const int nl = g * 64 + lane;

  float acc[32];
  {
    const float* bp = b1 + q * 32;
    #pragma unroll
    for (int i = 0; i < 32; ++i) acc[i] = bp[i];
  }
  {
    const float* w = W1 + q * 32;
    #pragma unroll 2
    for (int k4 = 0; k4 < 16; ++k4) {
      float4 xv = x4[k4];
      sfma32(acc, xv.x, w);
      sfma32(acc, xv.y, w + E);
      sfma32(acc, xv.z, w + 2 * E);
      sfma32(acc, xv.w, w + 3 * E);
      w += 4 * E;
    }
  }
  {
    float4* trow = (float4*)&tl[nl * 68 + q * 32];
    #pragma unroll
    for (int i = 0; i < 8; ++i)
      trow[i] = make_float4(fmaxf(acc[4*i], 0.f), fmaxf(acc[4*i+1], 0.f),
                            fmaxf(acc[4*i+2], 0.f), fmaxf(acc[4*i+3], 0.f));
  }
  __syncthreads();

  float o[32];
  {
    const float* bp = b2 + q * 32;
    #pragma unroll
    for (int i = 0; i < 32; ++i) o[i] = bp[i];
  }
  {
    const float4* tr = (const float4*)&tl[nl * 68];
    const float* w = W2 + q * 32;
    #pragma unroll 4
    for (int kk = 0; kk < 16; ++kk) {
      float4 tv = tr[kk];
      sfma32(o, tv.x, w);
      sfma32(o, tv.y, w + E);
      sfma32(o, tv.z, w + 2 * E);
      sfma32(o, tv.w, w + 3 * E);
      w += 4 * E;
    }
  }
  if (valid) {
    float cf = (float)cnt_u[nc];
    float4* ap = (float4*)(agg + (size_t)n * E + q * 32);
    #pragma unroll
    for (int i = 0; i < 8; ++i)
      ap[i] = make_float4(o[4*i] * cf, o[4*i+1] * cf, o[4*i+2] * cf, o[4*i+3] * cf);
  }
}

// -------- edge messages, PAB mode (b1 pre-folded into Pa) --------
__global__ void __launch_bounds__(256) k_edge_pab(
    const int* __restrict__ rel_e, const float* __restrict__ Pab,
    const float* __restrict__ W2, const float* __restrict__ b2,
    float* __restrict__ msgbuf, int me)
{
  __shared__ __align__(16) float tl[64 * 132];
  const int tid = threadIdx.x;
  const int lane = tid & 63;
  const int wq = __builtin_amdgcn_readfirstlane(tid >> 6);
  const int e = blockIdx.x * 64 + lane;
  const bool valid = (e < me);
  const int ec = valid ? e : (me - 1);
  const int s = rel_e[2 * ec], d = rel_e[2 * ec + 1];

  {
    const float4* pa = (const float4*)(Pab + (size_t)s * 256 + wq * 32);
    const float4* pb = (const float4*)(Pab + (size_t)d * 256 + 128 + wq * 32);
    float4* trow = (float4*)&tl[lane * 132 + wq * 32];
    #pragma unroll
    for (int i = 0; i < 8; ++i) {
      float4 va = pa[i], vb = pb[i];
      trow[i] = make_float4(fmaxf(va.x + vb.x, 0.f), fmaxf(va.y + vb.y, 0.f),
                            fmaxf(va.z + vb.z, 0.f), fmaxf(va.w + vb.w, 0.f));
    }
  }
  __syncthreads();

  float o[32];
  {
    const float* bp = b2 + wq * 32;
    #pragma unroll
    for (int i = 0; i < 32; ++i) o[i] = bp[i];
  }
  {
    const float4* tr = (const float4*)&tl[lane * 132];
    const float* w = W2 + wq * 32;
    #pragma unroll 4
    for (int kk = 0; kk < 32; ++kk) {
      float4 tv = tr[kk];
      sfma32(o, tv.x, w);
      sfma32(o, tv.y, w + TWO_E);
      sfma32(o, tv.z, w + 2 * TWO_E);
      sfma32(o, tv.w, w + 3 * TWO_E);
      w += 4 * TWO_E;
    }
  }
  if (valid) {
    size_t slot = 2 * (size_t)e + (wq >> 1);
    float4* mp = (float4*)(msgbuf + slot * E + (wq & 1) * 32);
    #pragma unroll
    for (int i = 0; i < 8; ++i)
      mp[i] = make_float4(o[4*i], o[4*i+1], o[4*i+2], o[4*i+3]);
  }
}

// -------- edge messages, fallback (reads h; used only if ws too small) ------
__global__ void __launch_bounds__(256) k_edge_fb(
    const int* __restrict__ rel_e, const float* __restrict__ h,
    const float* __restrict__ W1, const float* __restrict__ b1,
    const float* __restrict__ W2, const float* __restrict__ b2,
    float* __restrict__ msgbuf, int me)
{
  __shared__ __align__(16) float tl[64 * 132];
  const int tid = threadIdx.x;
  const int lane = tid & 63;
  const int wq = __builtin_amdgcn_readfirstlane(tid >> 6);
  const int e = blockIdx.x * 64 + lane;
  const bool valid = (e < me);
  const int ec = valid ? e : (me - 1);
  const int s = rel_e[2 * ec], d = rel_e[2 * ec + 1];
  const float4* xs4 = (const float4*)(h + (size_t)s * E);
  const float4* xd4 = (const float4*)(h + (size_t)d * E);

  float acc[32];
  {
    const float* bp = b1 + wq * 32;
    #pragma unroll
    for (int i = 0; i < 32; ++i) acc[i] = bp[i];
  }
  {
    const float* w = W1 + wq * 32;
    #pragma unroll 2
    for (int k4 = 0; k4 < 16; ++k4) {
      float4 xv = xs4[k4];
      sfma32(acc, xv.x, w);
      sfma32(acc, xv.y, w + TWO_E);
      sfma32(acc, xv.z, w + 2 * TWO_E);
      sfma32(acc, xv.w, w + 3 * TWO_E);
      w += 4 * TWO_E;
    }
    #pragma unroll 2
    for (int k4 = 0; k4 < 16; ++k4) {
      float4 xv = xd4[k4];
      sfma32(acc, xv.x, w);
      sfma32(acc, xv.y, w + TWO_E);
      sfma32(acc, xv.z, w + 2 * TWO_E);
      sfma32(acc, xv.w, w + 3 * TWO_E);
      w += 4 * TWO_E;
    }
  }
  {
    float4* trow = (float4*)&tl[lane * 132 + wq * 32];
    #pragma unroll
    for (int i = 0; i < 8; ++i)
      trow[i] = make_float4(fmaxf(acc[4*i], 0.f), fmaxf(acc[4*i+1], 0.f),
                            fmaxf(acc[4*i+2], 0.f), fmaxf(acc[4*i+3], 0.f));
  }
  __syncthreads();

  float o[32];
  {
    const float* bp = b2 + wq * 32;
    #pragma unroll
    for (int i = 0; i < 32; ++i) o[i] = bp[i];
  }
  {
    const float4* tr = (const float4*)&tl[lane * 132];
    const float* w = W2 + wq * 32;
    #pragma unroll 4
    for (int kk = 0; kk < 32; ++kk) {
      float4 tv = tr[kk];
      sfma32(o, tv.x, w);
      sfma32(o, tv.y, w + TWO_E);
      sfma32(o, tv.z, w + 2 * TWO_E);
      sfma32(o, tv.w, w + 3 * TWO_E);
      w += 4 * TWO_E;
    }
  }
  if (valid) {
    size_t slot = 2 * (size_t)e + (wq >> 1);
    float4* mp = (float4*)(msgbuf + slot * E + (wq & 1) * 32);
    #pragma unroll
    for (int i = 0; i < 8; ++i)
      mp[i] = make_float4(o[4*i], o[4*i+1], o[4*i+2], o[4*i+3]);
  }
}

// ------- gather: agg[n] += sum msgbuf[slots of n] ----------
__global__ void __launch_bounds__(256) k_gather(
    const float* __restrict__ msgbuf, const int* __restrict__ idx,
    const int* __restrict__ startp, float* __restrict__ agg, int nn)
{
  int wave = threadIdx.x >> 6;
  int j = threadIdx.x & 63;
  int n = blockIdx.x * 4 + wave;
  if (n >= nn) return;
  int s0 = startp[n], s1 = startp[n + 1];
  float v = agg[(size_t)n * E + j];
  for (int i = s0; i < s1; ++i) {
    int m = idx[i];
    v += msgbuf[(size_t)m * E + j];
  }
  agg[(size_t)n * E + j] = v;
}

// ------- fused readout+proj: one block per graph (contiguous node runs) ----
__global__ void __launch_bounds__(256) k_readout_g(
    const float* __restrict__ h, const int* __restrict__ gids,
    const float* __restrict__ Wr, const float* __restrict__ br,
    float* __restrict__ g, int nn, int npg)
{
  __shared__ float ls[4][64];
  __shared__ float grow[64];
  const int j = threadIdx.x & 63;
  const int w = threadIdx.x >> 6;
  const int base = blockIdx.x * npg;
  float acc = 0.f;
  for (int i = w; i < npg; i += 4) {
    int node = base + i;
    if (node < nn) acc += h[(size_t)node * 64 + j];
  }
  ls[w][j] = acc;
  __syncthreads();
  if (w == 0) grow[j] = ls[0][j] + ls[1][j] + ls[2][j] + ls[3][j];
  __syncthreads();
  float p = 0.f;
  #pragma unroll
  for (int kk = 0; kk < 16; ++kk) {
    int k = w * 16 + kk;
    p = fmaf(grow[k], Wr[k * 64 + j], p);
  }
  ls[w][j] = p;
  __syncthreads();
  if (w == 0) {
    int gout = gids[base];
    g[gout * 64 + j] = ls[0][j] + ls[1][j] + ls[2][j] + ls[3][j] + br[j];
  }
}

// -------- node update: h[n] += LN(MLPu([h,agg])) + LN(MLPg([h,g[gid]])) -----
__global__ void __launch_bounds__(256) k_update(
    float* __restrict__ h, const float* __restrict__ agg,
    const float* __restrict__ gvec, const int* __restrict__ gids,
    const float* __restrict__ Wu1, const float* __restrict__ bu1,
    const float* __restrict__ Wu2, const float* __restrict__ bu2,
    const float* __restrict__ Wg1, const float* __restrict__ bg1,
    const float* __restrict__ Wg2, const float* __restrict__ bg2,
    const float* __restrict__ lnw, const float* __restrict__ lnb,
    int nn)
{
  __shared__ __align__(16) float tl[128 * 68];
  __shared__ float st[128 * 5];
  const int tid = threadIdx.x;
  const int lane = tid & 63;
  const int wq = __builtin_amdgcn_readfirstlane(tid >> 6);
  const int g = wq >> 1, q = wq & 1;
  const int n = blockIdx.x * 128 + g * 64 + lane;
  const bool valid = (n < nn);
  const int ncl = valid ? n : (nn - 1);
  const int gid = gids[ncl];
  const float4* hx = (const float4*)(h + (size_t)ncl * E);
  const float4* ax = (const float4*)(agg + (size_t)ncl * E);
  const float4* gx = (const float4*)(gvec + (size_t)gid * E);
  const int nl = g * 64 + lane;

  float res[32];

  #pragma unroll
  for (int pass = 0; pass < 2; ++pass) {
    const float* W1 = (pass == 0) ? Wu1 : Wg1;
    const float* B1 = (pass == 0) ? bu1 : bg1;
    const float* W2 = (pass == 0) ? Wu2 : Wg2;
    const float* B2 = (pass == 0) ? bu2 : bg2;
    const float4* xb = (pass == 0) ? ax : gx;

    float acc[32];
    {
      const float* bp = B1 + q * 32;
      #pragma unroll
      for (int i = 0; i < 32; ++i) acc[i] = bp[i];
    }
    {
      const float* w = W1 + q * 32;
      #pragma unroll 2
      for (int k4 = 0; k4 < 16; ++k4) {
        float4 xv = hx[k4];
        sfma32(acc, xv.x, w);
        sfma32(acc, xv.y, w + E);
        sfma32(acc, xv.z, w + 2 * E);
        sfma32(acc, xv.w, w + 3 * E);
        w += 4 * E;
      }
      #pragma unroll 2
      for (int k4 = 0; k4 < 16; ++k4) {
        float4 xv = xb[k4];
        sfma32(acc, xv.x, w);
        sfma32(acc, xv.y, w + E);
        sfma32(acc, xv.z, w + 2 * E);
        sfma32(acc, xv.w, w + 3 * E);
        w += 4 * E;
      }
    }
    __syncthreads();
    {
      float4* trow = (float4*)&tl[nl * 68 + q * 32];
      #pragma unroll
      for (int i = 0; i < 8; ++i)
        trow[i] = make_float4(fmaxf(acc[4*i], 0.f), fmaxf(acc[4*i+1], 0.f),
                              fmaxf(acc[4*i+2], 0.f), fmaxf(acc[4*i+3], 0.f));
    }
    __syncthreads();

    float o[32];
    {
      const float* bp = B2 + q * 32;
      #pragma unroll
      for (int i = 0; i < 32; ++i) o[i] = bp[i];
    }
    {
      const float4* tr = (const float4*)&tl[nl * 68];
      const float* w = W2 + q * 32;
      #pragma unroll 4
      for (int kk = 0; kk < 16; ++kk) {
        float4 tv = tr[kk];
        sfma32(o, tv.x, w);
        sfma32(o, tv.y, w + E);
        sfma32(o, tv.z, w + 2 * E);
        sfma32(o, tv.w, w + 3 * E);
        w += 4 * E;
      }
    }

    float s1 = 0.f;
    #pragma unroll
    for (int i = 0; i < 32; ++i) s1 += o[i];
    st[nl * 5 + q] = s1;
    __syncthreads();
    float mu = (st[nl * 5 + 0] + st[nl * 5 + 1]) * (1.f / E);
    float s2 = 0.f;
    #pragma unroll
    for (int i = 0; i < 32; ++i) { float dm = o[i] - mu; s2 += dm * dm; }
    st[nl * 5 + 2 + q] = s2;
    __syncthreads();
    float var = (st[nl * 5 + 2] + st[nl * 5 + 3]) * (1.f / E);
    float rs = rsqrtf(var + 1e-5f);
    {
      const float* lw = lnw + q * 32;
      const float* lb = lnb + q * 32;
      #pragma unroll
      for (int i = 0; i < 32; ++i) {
        float v = (o[i] - mu) * rs * lw[i] + lb[i];
        if (pass == 0) res[i] = v; else res[i] += v;
      }
    }
  }

  if (valid) {
    float4* hw = (float4*)(h + (size_t)n * E + q * 32);
    #pragma unroll
    for (int i = 0; i < 8; ++i) {
      float4 hv = hw[i];
      hw[i] = make_float4(hv.x + res[4*i], hv.y + res[4*i+1],
                          hv.z + res[4*i+2], hv.w + res[4*i+3]);
    }
  }
}

extern "C" void kernel_launch(void* const* d_in, const int* in_sizes, int n_in,
                              void* d_out, int out_size, void* d_ws, size_t ws_size,
                              hipStream_t stream) {
  (void)n_in; (void)out_size;
  const int*   rel_u = (const int*)d_in[0];
  const int*   rel_e = (const int*)d_in[1];
  const int*   gids  = (const int*)d_in[2];
  const float* Wm1_u = (const float*)d_in[4];
  const float* bm1_u = (const float*)d_in[5];
  const float* Wm2_u = (const float*)d_in[6];
  const float* bm2_u = (const float*)d_in[7];
  const float* Wm1_e = (const float*)d_in[8];
  const float* bm1_e = (const float*)d_in[9];
  const float* Wm2_e = (const float*)d_in[10];
  const float* bm2_e = (const float*)d_in[11];
  const float* Wu1   = (const float*)d_in[12];
  const float* bu1   = (const float*)d_in[13];
  const float* Wu2   = (const float*)d_in[14];
  const float* bu2   = (const float*)d_in[15];
  const float* lnw   = (const float*)d_in[16];
  const float* lnb   = (const float*)d_in[17];
  const float* Wr    = (const float*)d_in[18];
  const float* br    = (const float*)d_in[19];
  const float* Wg1   = (const float*)d_in[20];
  const float* bg1   = (const float*)d_in[21];
  const float* Wg2   = (const float*)d_in[22];
  const float* bg2   = (const float*)d_in[23];

  const int MU_ = in_sizes[0];          // 100000
  const int ME_ = in_sizes[1] / 2;      // 200000
  const int NN  = in_sizes[2];          // 50000
  const int GN  = 100;
  const int NPG = NN / GN;              // 500 nodes per graph (contiguous)
  const int M2  = 2 * ME_;              // 400000 edge message slots

  // ---- workspace layout ----
  float* h      = (float*)d_out;
  float* agg    = (float*)d_ws;                            // [N*64]
  float* g      = agg + (size_t)NN * E;                    // [G*64]
  float* mu0    = g + (size_t)GN * E;                      // [64]
  float* me0    = mu0 + 64;                                // [128]
  float* msgbuf = me0 + TWO_E;                             // [M2*64]
  int*   cnt    = (int*)(msgbuf + (size_t)M2 * E);         // [N]
  int*   startp = cnt + NN;                                // [N+1]
  int*   cursor = startp + NN + 1;                         // [N]
  int*   cnt_u  = cursor + NN;                             // [N]
  int*   cpos0  = cnt_u + NN;                              // [N]
  int*   cpos1  = cpos0 + NN;                              // [N]
  int*   idxl   = cpos1 + NN;                              // [M2]
  size_t int_end = (size_t)(idxl + M2 - (int*)d_ws);
  size_t pab_off = (int_end + 3) & ~(size_t)3;
  float* Pab    = (float*)d_ws + pab_off;                  // [N*256]
  size_t need_pab = (pab_off + (size_t)NN * 256) * 4;
  const bool pab_mode = (ws_size >= need_pab);

  { // h = 0
    int n4 = NN * E / 4;
    k_zero<<<(n4 + 255) / 256, 256, 0, stream>>>((float4*)h, n4);
  }
  { // zero int region cnt..cpos1 (6N+1 ints; spill into idxl[0..2] is ok)
    int n4 = (6 * NN + 4) / 4;
    k_zero<<<(n4 + 255) / 256, 256, 0, stream>>>((float4*)cnt, n4);
  }
  // ---- CSR + counts + constant messages (once; graph static) ----
  k_count_e<<<(M2 + 255) / 256, 256, 0, stream>>>(rel_e, cnt, cpos0, cpos1, M2);
  k_count_u<<<(MU_ + 255) / 256, 256, 0, stream>>>(rel_u, cnt_u, MU_);
  k_scan<<<1, 1024, 0, stream>>>(cnt, startp, NN, M2);
  k_copyint<<<(NN + 255) / 256, 256, 0, stream>>>(startp, cursor, NN);
  k_fill_e<<<(M2 + 255) / 256, 256, 0, stream>>>(rel_e, cursor, idxl, M2);
  k_mlp0<<<1, 128, 0, stream>>>(bm1_u, Wm2_u, bm2_u, bm1_e, Wm2_e, bm2_e,
                                br, mu0, me0, g, GN);

  // ---- layer 0: h = 0 -> messages constant; g = br (written by k_mlp0) ----
  k_agg0<<<(NN * 16 + 255) / 256, 256, 0, stream>>>(cnt_u, cpos0, cpos1, mu0, me0, agg, NN);
  k_update<<<(NN + 127) / 128, 256, 0, stream>>>(
      h, agg, g, gids, Wu1, bu1, Wu2, bu2, Wg1, bg1, Wg2, bg2, lnw, lnb, NN);

  // ---- layers 1..3 ----
  for (int l = 1; l < 4; ++l) {
    if (pab_mode) {
      k_pab<<<(NN + 63) / 64, 256, 0, stream>>>(h, Wm1_e, bm1_e, Pab, NN);
      k_edge_pab<<<(ME_ + 63) / 64, 256, 0, stream>>>(
          rel_e, Pab, Wm2_e, bm2_e, msgbuf, ME_);
    } else {
      k_edge_fb<<<(ME_ + 63) / 64, 256, 0, stream>>>(
          rel_e, h, Wm1_e, bm1_e, Wm2_e, bm2_e, msgbuf, ME_);
    }
    k_umsg_agg<<<(NN + 127) / 128, 256, 0, stream>>>(
        h, cnt_u, Wm1_u, bm1_u, Wm2_u, bm2_u, agg, NN);
    k_gather<<<(NN + 3) / 4, 256, 0, stream>>>(msgbuf, idxl, startp, agg, NN);
    k_readout_g<<<GN, 256, 0, stream>>>(h, gids, Wr, br, g, NN, NPG);
    k_update<<<(NN + 127) / 128, 256, 0, stream>>>(
        h, agg, g, gids, Wu1, bu1, Wu2, bu2, Wg1, bg1, Wg2, bg2, lnw, lnb, NN);
  }
}

// Round 8
// 1185.054 us; speedup vs baseline: 1.2209x; 1.2209x over previous
//
#include <hip/hip_runtime.h>

// Round 8: k_pab inverted to lane=node (k_umsg-style). Per-lane coalesced h
// loads (float4, reused over 64 output cols), wave-uniform scalar-pipe
// weights, out[64] register-resident, coalesced-ish float4 stores.
// Everything else identical to round 7 (minus the failed vpin broadcast).

#define E 64
#define TWO_E 128

__device__ __forceinline__ void sfma32(float (&acc)[32], float xu, const float* w) {
  #pragma unroll
  for (int i = 0; i < 32; ++i) acc[i] = fmaf(xu, w[i], acc[i]);
}

// ---------------- zero ----------------
__global__ void k_zero(float4* __restrict__ p, int n4) {
  int i = blockIdx.x * blockDim.x + threadIdx.x;
  if (i < n4) p[i] = make_float4(0.f, 0.f, 0.f, 0.f);
}

// ---------------- CSR build (once per launch; edge slots only) ----------------
__global__ void k_count_e(const int* __restrict__ rel_e, int* __restrict__ cnt,
                          int* __restrict__ cpos0, int* __restrict__ cpos1, int M2) {
  int q = blockIdx.x * blockDim.x + threadIdx.x;
  if (q >= M2) return;
  int n = rel_e[q];
  atomicAdd(&cnt[n], 1);
  atomicAdd(&((q & 1) ? cpos1 : cpos0)[n], 1);
}
__global__ void k_count_u(const int* __restrict__ rel_u, int* __restrict__ cnt_u, int mu) {
  int m = blockIdx.x * blockDim.x + threadIdx.x;
  if (m >= mu) return;
  atomicAdd(&cnt_u[rel_u[m]], 1);
}

__global__ void __launch_bounds__(1024) k_scan(const int* __restrict__ cnt,
                                               int* __restrict__ startp, int nn, int M2) {
  __shared__ int ls[1024];
  int t = threadIdx.x;
  const int C = 49;                        // 49*1024 >= 50000
  int c0 = t * C, c1 = min(c0 + C, nn);
  int s = 0;
  for (int i = c0; i < c1; ++i) s += cnt[i];
  ls[t] = s;
  __syncthreads();
  for (int off = 1; off < 1024; off <<= 1) {
    int v = (t >= off) ? ls[t - off] : 0;
    __syncthreads();
    ls[t] += v;
    __syncthreads();
  }
  int run = (t > 0) ? ls[t - 1] : 0;
  for (int i = c0; i < c1; ++i) { startp[i] = run; run += cnt[i]; }
  if (t == 1023) startp[nn] = M2;
}

__global__ void k_copyint(const int* __restrict__ a, int* __restrict__ b, int n) {
  int i = blockIdx.x * blockDim.x + threadIdx.x;
  if (i < n) b[i] = a[i];
}

__global__ void k_fill_e(const int* __restrict__ rel_e, int* __restrict__ cursor,
                         int* __restrict__ idx, int M2) {
  int q = blockIdx.x * blockDim.x + threadIdx.x;
  if (q >= M2) return;
  int p = atomicAdd(&cursor[rel_e[q]], 1);
  idx[p] = q;
}

// ------- mu0 = MLP_u(0), me0 = MLP_e(0); also g(layer0) = br for all graphs ----
__global__ void k_mlp0(const float* __restrict__ b1u, const float* __restrict__ W2u,
                       const float* __restrict__ b2u,
                       const float* __restrict__ b1e, const float* __restrict__ W2e,
                       const float* __restrict__ b2e,
                       const float* __restrict__ br,
                       float* __restrict__ mu0, float* __restrict__ me0,
                       float* __restrict__ g, int gn) {
  __shared__ float hu[64], he[128];
  int t = threadIdx.x;                     // 128 threads
  if (t < 64) hu[t] = fmaxf(b1u[t], 0.f);
  he[t] = fmaxf(b1e[t], 0.f);
  __syncthreads();
  if (t < 64) {
    float a = b2u[t];
    for (int k = 0; k < 64; ++k) a = fmaf(hu[k], W2u[k * 64 + t], a);
    mu0[t] = a;
  }
  float a = b2e[t];
  for (int k = 0; k < 128; ++k) a = fmaf(he[k], W2e[k * TWO_E + t], a);
  me0[t] = a;
  if (t < 64) {
    float b = br[t];
    for (int gi = 0; gi < gn; ++gi) g[gi * 64 + t] = b;
  }
}

// ------- layer-0 agg from counts ----------
__global__ void k_agg0(const int* __restrict__ cnt_u, const int* __restrict__ cpos0,
                       const int* __restrict__ cpos1, const float* __restrict__ mu0,
                       const float* __restrict__ me0, float* __restrict__ agg, int nn) {
  int i = blockIdx.x * blockDim.x + threadIdx.x;   // (n, j4)
  int n = i >> 4, j4 = i & 15;
  if (n >= nn) return;
  float cu = (float)cnt_u[n], c0 = (float)cpos0[n], c1 = (float)cpos1[n];
  float4 m = ((const float4*)mu0)[j4];
  float4 a = ((const float4*)me0)[j4];
  float4 b = ((const float4*)(me0 + 64))[j4];
  ((float4*)agg)[i] = make_float4(cu * m.x + c0 * a.x + c1 * b.x,
                                  cu * m.y + c0 * a.y + c1 * b.y,
                                  cu * m.z + c0 * a.z + c1 * b.z,
                                  cu * m.w + c0 * a.w + c1 * b.w);
}

// ---------------- Pab[n] = [h[n]@W1_top + b1 | h[n]@W1_bot] ----------------
// lane = node, wave wq owns 64-col output chunk. h loads per-lane float4
// (coalesced, reused across 64 cols); weights wave-uniform scalar-pipe;
// out[64] register-resident; 16 float4 stores per thread.
__global__ void __launch_bounds__(256) k_pab(
    const float* __restrict__ h, const float* __restrict__ W1,  // [128][128]
    const float* __restrict__ b1, float* __restrict__ Pab, int nn)
{
  const int lane = threadIdx.x & 63;
  const int wq = __builtin_amdgcn_readfirstlane(threadIdx.x >> 6);  // 0..3
  const int c0 = wq * 64;                        // out col chunk in [0,256)
  const int rbase = (c0 < 128) ? 0 : 64;         // W1 row block (top/bot)
  const int cw = (c0 < 128) ? c0 : (c0 - 128);
  const int node = blockIdx.x * 64 + lane;
  const bool valid = (node < nn);
  const int nc = valid ? node : (nn - 1);
  const float4* h4 = (const float4*)(h + (size_t)nc * E);

  float out[64];
  #pragma unroll
  for (int j = 0; j < 64; ++j) out[j] = 0.f;

  const float* w = W1 + rbase * TWO_E + cw;      // wave-uniform, row stride 128
  for (int k4 = 0; k4 < 16; ++k4) {
    float4 hv = h4[k4];
    #pragma unroll
    for (int u = 0; u < 4; ++u) {
      float hk = (u == 0) ? hv.x : (u == 1) ? hv.y : (u == 2) ? hv.z : hv.w;
      #pragma unroll
      for (int j = 0; j < 64; ++j) out[j] = fmaf(hk, w[j], out[j]);
      w += TWO_E;
    }
  }
  if (c0 < 128) {                                // fold b1 into Pa half
    #pragma unroll
    for (int j = 0; j < 64; ++j) out[j] += b1[cw + j];
  }
  if (valid) {
    float4* op = (float4*)(Pab + (size_t)node * 256 + c0);
    #pragma unroll
    for (int i = 0; i < 16; ++i)
      op[i] = make_float4(out[4*i], out[4*i+1], out[4*i+2], out[4*i+3]);
  }
}

// ------- unary agg init: agg[n] = cnt_u[n] * MLP_u(h[n]) ----------
__global__ void __launch_bounds__(256) k_umsg_agg(
    const float* __restrict__ h, const int* __restrict__ cnt_u,
    const float* __restrict__ W1, const float* __restrict__ b1,
    const float* __restrict__ W2, const float* __restrict__ b2,
    float* __restrict__ agg, int nn)
{
  __shared__ __align__(16) float tl[128 * 68];
  const int tid = threadIdx.x;
  const int lane = tid & 63;
  const int wq = __builtin_amdgcn_readfirstlane(tid >> 6);
  const int g = wq >> 1, q = wq & 1;
  const int n = blockIdx.x * 128 + g * 64 + lane;
  const bool valid = (n < nn);
  const int nc = valid ? n : (nn - 1);
  const float4* x4 = (const float4*)(h + (size_t)nc * E);
  const int nl = g * 64 + lane;

  float acc[32];
  {
    const float* bp = b1 + q * 32;
    #pragma unroll
    for (int i = 0; i < 32; ++i) acc[i] = bp[i];
  }
  {
    const float* w = W1 + q * 32;
    #pragma unroll 2
    for (int k4 = 0; k4 < 16; ++k4) {
      float4 xv = x4[k4];
      sfma32(acc, xv.x, w);
      sfma32(acc, xv.y, w + E);
      sfma32(acc, xv.z, w + 2 * E);
      sfma32(acc, xv.w, w + 3 * E);
      w += 4 * E;
    }
  }
  {
    float4* trow = (float4*)&tl[nl * 68 + q * 32];
    #pragma unroll
    for (int i = 0; i < 8; ++i)
      trow[i] = make_float4(fmaxf(acc[4*i], 0.f), fmaxf(acc[4*i+1], 0.f),
                            fmaxf(acc[4*i+2], 0.f), fmaxf(acc[4*i+3], 0.f));
  }
  __syncthreads();

  float o[32];
  {
    const float* bp = b2 + q * 32;
    #pragma unroll
    for (int i = 0; i < 32; ++i) o[i] = bp[i];
  }
  {
    const float4* tr = (const float4*)&tl[nl * 68];
    const float* w = W2 + q * 32;
    #pragma unroll 4
    for (int kk = 0; kk < 16; ++kk) {
      float4 tv = tr[kk];
      sfma32(o, tv.x, w);
      sfma32(o, tv.y, w + E);
      sfma32(o, tv.z, w + 2 * E);
      sfma32(o, tv.w, w + 3 * E);
      w += 4 * E;
    }
  }
  if (valid) {
    float cf = (float)cnt_u[nc];
    float4* ap = (float4*)(agg + (size_t)n * E + q * 32);
    #pragma unroll
    for (int i = 0; i < 8; ++i)
      ap[i] = make_float4(o[4*i] * cf, o[4*i+1] * cf, o[4*i+2] * cf, o[4*i+3] * cf);
  }
}

// -------- edge messages, PAB mode (b1 pre-folded into Pa) --------
__global__ void __launch_bounds__(256) k_edge_pab(
    const int* __restrict__ rel_e, const float* __restrict__ Pab,
    const float* __restrict__ W2, const float* __restrict__ b2,
    float* __restrict__ msgbuf, int me)
{
  __shared__ __align__(16) float tl[64 * 132];
  const int tid = threadIdx.x;
  const int lane = tid & 63;
  const int wq = __builtin_amdgcn_readfirstlane(tid >> 6);
  const int e = blockIdx.x * 64 + lane;
  const bool valid = (e < me);
  const int ec = valid ? e : (me - 1);
  const int s = rel_e[2 * ec], d = rel_e[2 * ec + 1];

  {
    const float4* pa = (const float4*)(Pab + (size_t)s * 256 + wq * 32);
    const float4* pb = (const float4*)(Pab + (size_t)d * 256 + 128 + wq * 32);
    float4* trow = (float4*)&tl[lane * 132 + wq * 32];
    #pragma unroll
    for (int i = 0; i < 8; ++i) {
      float4 va = pa[i], vb = pb[i];
      trow[i] = make_float4(fmaxf(va.x + vb.x, 0.f), fmaxf(va.y + vb.y, 0.f),
                            fmaxf(va.z + vb.z, 0.f), fmaxf(va.w + vb.w, 0.f));
    }
  }
  __syncthreads();

  float o[32];
  {
    const float* bp = b2 + wq * 32;
    #pragma unroll
    for (int i = 0; i < 32; ++i) o[i] = bp[i];
  }
  {
    const float4* tr = (const float4*)&tl[lane * 132];
    const float* w = W2 + wq * 32;
    #pragma unroll 4
    for (int kk = 0; kk < 32; ++kk) {
      float4 tv = tr[kk];
      sfma32(o, tv.x, w);
      sfma32(o, tv.y, w + TWO_E);
      sfma32(o, tv.z, w + 2 * TWO_E);
      sfma32(o, tv.w, w + 3 * TWO_E);
      w += 4 * TWO_E;
    }
  }
  if (valid) {
    size_t slot = 2 * (size_t)e + (wq >> 1);
    float4* mp = (float4*)(msgbuf + slot * E + (wq & 1) * 32);
    #pragma unroll
    for (int i = 0; i < 8; ++i)
      mp[i] = make_float4(o[4*i], o[4*i+1], o[4*i+2], o[4*i+3]);
  }
}

// -------- edge messages, fallback (reads h; used only if ws too small) ------
__global__ void __launch_bounds__(256) k_edge_fb(
    const int* __restrict__ rel_e, const float* __restrict__ h,
    const float* __restrict__ W1, const float* __restrict__ b1,
    const float* __restrict__ W2, const float* __restrict__ b2,
    float* __restrict__ msgbuf, int me)
{
  __shared__ __align__(16) float tl[64 * 132];
  const int tid = threadIdx.x;
  const int lane = tid & 63;
  const int wq = __builtin_amdgcn_readfirstlane(tid >> 6);
  const int e = blockIdx.x * 64 + lane;
  const bool valid = (e < me);
  const int ec = valid ? e : (me - 1);
  const int s = rel_e[2 * ec], d = rel_e[2 * ec + 1];
  const float4* xs4 = (const float4*)(h + (size_t)s * E);
  const float4* xd4 = (const float4*)(h + (size_t)d * E);

  float acc[32];
  {
    const float* bp = b1 + wq * 32;
    #pragma unroll
    for (int i = 0; i < 32; ++i) acc[i] = bp[i];
  }
  {
    const float* w = W1 + wq * 32;
    #pragma unroll 2
    for (int k4 = 0; k4 < 16; ++k4) {
      float4 xv = xs4[k4];
      sfma32(acc, xv.x, w);
      sfma32(acc, xv.y, w + TWO_E);
      sfma32(acc, xv.z, w + 2 * TWO_E);
      sfma32(acc, xv.w, w + 3 * TWO_E);
      w += 4 * TWO_E;
    }
    #pragma unroll 2
    for (int k4 = 0; k4 < 16; ++k4) {
      float4 xv = xd4[k4];
      sfma32(acc, xv.x, w);
      sfma32(acc, xv.y, w + TWO_E);
      sfma32(acc, xv.z, w + 2 * TWO_E);
      sfma32(acc, xv.w, w + 3 * TWO_E);
      w += 4 * TWO_E;
    }
  }
  {
    float4* trow = (float4*)&tl[lane * 132 + wq * 32];
    #pragma unroll
    for (int i = 0; i < 8; ++i)
      trow[i] = make_float4(fmaxf(acc[4*i], 0.f), fmaxf(acc[4*i+1], 0.f),
                            fmaxf(acc[4*i+2], 0.f), fmaxf(acc[4*i+3], 0.f));
  }
  __syncthreads();

  float o[32];
  {
    const float* bp = b2 + wq * 32;
    #pragma unroll
    for (int i = 0; i < 32; ++i) o[i] = bp[i];
  }
  {
    const float4* tr = (const float4*)&tl[lane * 132];
    const float* w = W2 + wq * 32;
    #pragma unroll 4
    for (int kk = 0; kk < 32; ++kk) {
      float4 tv = tr[kk];
      sfma32(o, tv.x, w);
      sfma32(o, tv.y, w + TWO_E);
      sfma32(o, tv.z, w + 2 * TWO_E);
      sfma32(o, tv.w, w + 3 * TWO_E);
      w += 4 * TWO_E;
    }
  }
  if (valid) {
    size_t slot = 2 * (size_t)e + (wq >> 1);
    float4* mp = (float4*)(msgbuf + slot * E + (wq & 1) * 32);
    #pragma unroll
    for (int i = 0; i < 8; ++i)
      mp[i] = make_float4(o[4*i], o[4*i+1], o[4*i+2], o[4*i+3]);
  }
}

// ------- gather: agg[n] += sum msgbuf[slots of n] ----------
__global__ void __launch_bounds__(256) k_gather(
    const float* __restrict__ msgbuf, const int* __restrict__ idx,
    const int* __restrict__ startp, float* __restrict__ agg, int nn)
{
  int wave = threadIdx.x >> 6;
  int j = threadIdx.x & 63;
  int n = blockIdx.x * 4 + wave;
  if (n >= nn) return;
  int s0 = startp[n], s1 = startp[n + 1];
  float v = agg[(size_t)n * E + j];
  for (int i = s0; i < s1; ++i) {
    int m = idx[i];
    v += msgbuf[(size_t)m * E + j];
  }
  agg[(size_t)n * E + j] = v;
}

// ------- fused readout+proj: one block per graph (contiguous node runs) ----
__global__ void __launch_bounds__(256) k_readout_g(
    const float* __restrict__ h, const int* __restrict__ gids,
    const float* __restrict__ Wr, const float* __restrict__ br,
    float* __restrict__ g, int nn, int npg)
{
  __shared__ float ls[4][64];
  __shared__ float grow[64];
  const int j = threadIdx.x & 63;
  const int w = threadIdx.x >> 6;
  const int base = blockIdx.x * npg;
  float acc = 0.f;
  for (int i = w; i < npg; i += 4) {
    int node = base + i;
    if (node < nn) acc += h[(size_t)node * 64 + j];
  }
  ls[w][j] = acc;
  __syncthreads();
  if (w == 0) grow[j] = ls[0][j] + ls[1][j] + ls[2][j] + ls[3][j];
  __syncthreads();
  float p = 0.f;
  #pragma unroll
  for (int kk = 0; kk < 16; ++kk) {
    int k = w * 16 + kk;
    p = fmaf(grow[k], Wr[k * 64 + j], p);
  }
  ls[w][j] = p;
  __syncthreads();
  if (w == 0) {
    int gout = gids[base];
    g[gout * 64 + j] = ls[0][j] + ls[1][j] + ls[2][j] + ls[3][j] + br[j];
  }
}

// -------- node update: h[n] += LN(MLPu([h,agg])) + LN(MLPg([h,g[gid]])) -----
__global__ void __launch_bounds__(256) k_update(
    float* __restrict__ h, const float* __restrict__ agg,
    const float* __restrict__ gvec, const int* __restrict__ gids,
    const float* __restrict__ Wu1, const float* __restrict__ bu1,
    const float* __restrict__ Wu2, const float* __restrict__ bu2,
    const float* __restrict__ Wg1, const float* __restrict__ bg1,
    const float* __restrict__ Wg2, const float* __restrict__ bg2,
    const float* __restrict__ lnw, const float* __restrict__ lnb,
    int nn)
{
  __shared__ __align__(16) float tl[128 * 68];
  __shared__ float st[128 * 5];
  const int tid = threadIdx.x;
  const int lane = tid & 63;
  const int wq = __builtin_amdgcn_readfirstlane(tid >> 6);
  const int g = wq >> 1, q = wq & 1;
  const int n = blockIdx.x * 128 + g * 64 + lane;
  const bool valid = (n < nn);
  const int ncl = valid ? n : (nn - 1);
  const int gid = gids[ncl];
  const float4* hx = (const float4*)(h + (size_t)ncl * E);
  const float4* ax = (const float4*)(agg + (size_t)ncl * E);
  const float4* gx = (const float4*)(gvec + (size_t)gid * E);
  const int nl = g * 64 + lane;

  float res[32];

  #pragma unroll
  for (int pass = 0; pass < 2; ++pass) {
    const float* W1 = (pass == 0) ? Wu1 : Wg1;
    const float* B1 = (pass == 0) ? bu1 : bg1;
    const float* W2 = (pass == 0) ? Wu2 : Wg2;
    const float* B2 = (pass == 0) ? bu2 : bg2;
    const float4* xb = (pass == 0) ? ax : gx;

    float acc[32];
    {
      const float* bp = B1 + q * 32;
      #pragma unroll
      for (int i = 0; i < 32; ++i) acc[i] = bp[i];
    }
    {
      const float* w = W1 + q * 32;
      #pragma unroll 2
      for (int k4 = 0; k4 < 16; ++k4) {
        float4 xv = hx[k4];
        sfma32(acc, xv.x, w);
        sfma32(acc, xv.y, w + E);
        sfma32(acc, xv.z, w + 2 * E);
        sfma32(acc, xv.w, w + 3 * E);
        w += 4 * E;
      }
      #pragma unroll 2
      for (int k4 = 0; k4 < 16; ++k4) {
        float4 xv = xb[k4];
        sfma32(acc, xv.x, w);
        sfma32(acc, xv.y, w + E);
        sfma32(acc, xv.z, w + 2 * E);
        sfma32(acc, xv.w, w + 3 * E);
        w += 4 * E;
      }
    }
    __syncthreads();
    {
      float4* trow = (float4*)&tl[nl * 68 + q * 32];
      #pragma unroll
      for (int i = 0; i < 8; ++i)
        trow[i] = make_float4(fmaxf(acc[4*i], 0.f), fmaxf(acc[4*i+1], 0.f),
                              fmaxf(acc[4*i+2], 0.f), fmaxf(acc[4*i+3], 0.f));
    }
    __syncthreads();

    float o[32];
    {
      const float* bp = B2 + q * 32;
      #pragma unroll
      for (int i = 0; i < 32; ++i) o[i] = bp[i];
    }
    {
      const float4* tr = (const float4*)&tl[nl * 68];
      const float* w = W2 + q * 32;
      #pragma unroll 4
      for (int kk = 0; kk < 16; ++kk) {
        float4 tv = tr[kk];
        sfma32(o, tv.x, w);
        sfma32(o, tv.y, w + E);
        sfma32(o, tv.z, w + 2 * E);
        sfma32(o, tv.w, w + 3 * E);
        w += 4 * E;
      }
    }

    float s1 = 0.f;
    #pragma unroll
    for (int i = 0; i < 32; ++i) s1 += o[i];
    st[nl * 5 + q] = s1;
    __syncthreads();
    float mu = (st[nl * 5 + 0] + st[nl * 5 + 1]) * (1.f / E);
    float s2 = 0.f;
    #pragma unroll
    for (int i = 0; i < 32; ++i) { float dm = o[i] - mu; s2 += dm * dm; }
    st[nl * 5 + 2 + q] = s2;
    __syncthreads();
    float var = (st[nl * 5 + 2] + st[nl * 5 + 3]) * (1.f / E);
    float rs = rsqrtf(var + 1e-5f);
    {
      const float* lw = lnw + q * 32;
      const float* lb = lnb + q * 32;
      #pragma unroll
      for (int i = 0; i < 32; ++i) {
        float v = (o[i] - mu) * rs * lw[i] + lb[i];
        if (pass == 0) res[i] = v; else res[i] += v;
      }
    }
  }

  if (valid) {
    float4* hw = (float4*)(h + (size_t)n * E + q * 32);
    #pragma unroll
    for (int i = 0; i < 8; ++i) {
      float4 hv = hw[i];
      hw[i] = make_float4(hv.x + res[4*i], hv.y + res[4*i+1],
                          hv.z + res[4*i+2], hv.w + res[4*i+3]);
    }
  }
}

extern "C" void kernel_launch(void* const* d_in, const int* in_sizes, int n_in,
                              void* d_out, int out_size, void* d_ws, size_t ws_size,
                              hipStream_t stream) {
  (void)n_in; (void)out_size;
  const int*   rel_u = (const int*)d_in[0];
  const int*   rel_e = (const int*)d_in[1];
  const int*   gids  = (const int*)d_in[2];
  const float* Wm1_u = (const float*)d_in[4];
  const float* bm1_u = (const float*)d_in[5];
  const float* Wm2_u = (const float*)d_in[6];
  const float* bm2_u = (const float*)d_in[7];
  const float* Wm1_e = (const float*)d_in[8];
  const float* bm1_e = (const float*)d_in[9];
  const float* Wm2_e = (const float*)d_in[10];
  const float* bm2_e = (const float*)d_in[11];
  const float* Wu1   = (const float*)d_in[12];
  const float* bu1   = (const float*)d_in[13];
  const float* Wu2   = (const float*)d_in[14];
  const float* bu2   = (const float*)d_in[15];
  const float* lnw   = (const float*)d_in[16];
  const float* lnb   = (const float*)d_in[17];
  const float* Wr    = (const float*)d_in[18];
  const float* br    = (const float*)d_in[19];
  const float* Wg1   = (const float*)d_in[20];
  const float* bg1   = (const float*)d_in[21];
  const float* Wg2   = (const float*)d_in[22];
  const float* bg2   = (const float*)d_in[23];

  const int MU_ = in_sizes[0];          // 100000
  const int ME_ = in_sizes[1] / 2;      // 200000
  const int NN  = in_sizes[2];          // 50000
  const int GN  = 100;
  const int NPG = NN / GN;              // 500 nodes per graph (contiguous)
  const int M2  = 2 * ME_;              // 400000 edge message slots

  // ---- workspace layout ----
  float* h      = (float*)d_out;
  float* agg    = (float*)d_ws;                            // [N*64]
  float* g      = agg + (size_t)NN * E;                    // [G*64]
  float* mu0    = g + (size_t)GN * E;                      // [64]
  float* me0    = mu0 + 64;                                // [128]
  float* msgbuf = me0 + TWO_E;                             // [M2*64]
  int*   cnt    = (int*)(msgbuf + (size_t)M2 * E);         // [N]
  int*   startp = cnt + NN;                                // [N+1]
  int*   cursor = startp + NN + 1;                         // [N]
  int*   cnt_u  = cursor + NN;                             // [N]
  int*   cpos0  = cnt_u + NN;                              // [N]
  int*   cpos1  = cpos0 + NN;                              // [N]
  int*   idxl   = cpos1 + NN;                              // [M2]
  size_t int_end = (size_t)(idxl + M2 - (int*)d_ws);
  size_t pab_off = (int_end + 3) & ~(size_t)3;
  float* Pab    = (float*)d_ws + pab_off;                  // [N*256]
  size_t need_pab = (pab_off + (size_t)NN * 256) * 4;
  const bool pab_mode = (ws_size >= need_pab);

  { // h = 0
    int n4 = NN * E / 4;
    k_zero<<<(n4 + 255) / 256, 256, 0, stream>>>((float4*)h, n4);
  }
  { // zero int region cnt..cpos1 (6N+1 ints; spill into idxl[0..2] is ok)
    int n4 = (6 * NN + 4) / 4;
    k_zero<<<(n4 + 255) / 256, 256, 0, stream>>>((float4*)cnt, n4);
  }
  // ---- CSR + counts + constant messages (once; graph static) ----
  k_count_e<<<(M2 + 255) / 256, 256, 0, stream>>>(rel_e, cnt, cpos0, cpos1, M2);
  k_count_u<<<(MU_ + 255) / 256, 256, 0, stream>>>(rel_u, cnt_u, MU_);
  k_scan<<<1, 1024, 0, stream>>>(cnt, startp, NN, M2);
  k_copyint<<<(NN + 255) / 256, 256, 0, stream>>>(startp, cursor, NN);
  k_fill_e<<<(M2 + 255) / 256, 256, 0, stream>>>(rel_e, cursor, idxl, M2);
  k_mlp0<<<1, 128, 0, stream>>>(bm1_u, Wm2_u, bm2_u, bm1_e, Wm2_e, bm2_e,
                                br, mu0, me0, g, GN);

  // ---- layer 0: h = 0 -> messages constant; g = br (written by k_mlp0) ----
  k_agg0<<<(NN * 16 + 255) / 256, 256, 0, stream>>>(cnt_u, cpos0, cpos1, mu0, me0, agg, NN);
  k_update<<<(NN + 127) / 128, 256, 0, stream>>>(
      h, agg, g, gids, Wu1, bu1, Wu2, bu2, Wg1, bg1, Wg2, bg2, lnw, lnb, NN);

  // ---- layers 1..3 ----
  for (int l = 1; l < 4; ++l) {
    if (pab_mode) {
      k_pab<<<(NN + 63) / 64, 256, 0, stream>>>(h, Wm1_e, bm1_e, Pab, NN);
      k_edge_pab<<<(ME_ + 63) / 64, 256, 0, stream>>>(
          rel_e, Pab, Wm2_e, bm2_e, msgbuf, ME_);
    } else {
      k_edge_fb<<<(ME_ + 63) / 64, 256, 0, stream>>>(
          rel_e, h, Wm1_e, bm1_e, Wm2_e, bm2_e, msgbuf, ME_);
    }
    k_umsg_agg<<<(NN + 127) / 128, 256, 0, stream>>>(
        h, cnt_u, Wm1_u, bm1_u, Wm2_u, bm2_u, agg, NN);
    k_gather<<<(NN + 3) / 4, 256, 0, stream>>>(msgbuf, idxl, startp, agg, NN);
    k_readout_g<<<GN, 256, 0, stream>>>(h, gids, Wr, br, g, NN, NPG);
    k_update<<<(NN + 127) / 128, 256, 0, stream>>>(
        h, agg, g, gids, Wu1, bu1, Wu2, bu2, Wg1, bg1, Wg2, bg2, lnw, lnb, NN);
  }
}

// Round 9
// 1096.257 us; speedup vs baseline: 1.3198x; 1.0810x over previous
//
#include <hip/hip_runtime.h>

// Round 9: tail cuts.
//  - CSR-permuted msgbuf: k_fill_e stores perm[slot]=CSR position; k_edge
//    writes messages directly at CSR position -> k_gather reads msgbuf
//    SEQUENTIALLY (no idx indirection, streaming).
//  - k_umsg fused into k_update epilogue (template DO_UMSG): h_new staged in
//    LDS, unary MLP computed there, agg written for next layer. 3 fewer
//    kernels + 3x h re-read eliminated.

#define E 64
#define TWO_E 128

__device__ __forceinline__ void sfma32(float (&acc)[32], float xu, const float* w) {
  #pragma unroll
  for (int i = 0; i < 32; ++i) acc[i] = fmaf(xu, w[i], acc[i]);
}

// ---------------- zero ----------------
__global__ void k_zero(float4* __restrict__ p, int n4) {
  int i = blockIdx.x * blockDim.x + threadIdx.x;
  if (i < n4) p[i] = make_float4(0.f, 0.f, 0.f, 0.f);
}

// ---------------- CSR build (once per launch; edge slots only) ----------------
__global__ void k_count_e(const int* __restrict__ rel_e, int* __restrict__ cnt,
                          int* __restrict__ cpos0, int* __restrict__ cpos1, int M2) {
  int q = blockIdx.x * blockDim.x + threadIdx.x;
  if (q >= M2) return;
  int n = rel_e[q];
  atomicAdd(&cnt[n], 1);
  atomicAdd(&((q & 1) ? cpos1 : cpos0)[n], 1);
}
__global__ void k_count_u(const int* __restrict__ rel_u, int* __restrict__ cnt_u, int mu) {
  int m = blockIdx.x * blockDim.x + threadIdx.x;
  if (m >= mu) return;
  atomicAdd(&cnt_u[rel_u[m]], 1);
}

__global__ void __launch_bounds__(1024) k_scan(const int* __restrict__ cnt,
                                               int* __restrict__ startp, int nn, int M2) {
  __shared__ int ls[1024];
  int t = threadIdx.x;
  const int C = 49;                        // 49*1024 >= 50000
  int c0 = t * C, c1 = min(c0 + C, nn);
  int s = 0;
  for (int i = c0; i < c1; ++i) s += cnt[i];
  ls[t] = s;
  __syncthreads();
  for (int off = 1; off < 1024; off <<= 1) {
    int v = (t >= off) ? ls[t - off] : 0;
    __syncthreads();
    ls[t] += v;
    __syncthreads();
  }
  int run = (t > 0) ? ls[t - 1] : 0;
  for (int i = c0; i < c1; ++i) { startp[i] = run; run += cnt[i]; }
  if (t == 1023) startp[nn] = M2;
}

__global__ void k_copyint(const int* __restrict__ a, int* __restrict__ b, int n) {
  int i = blockIdx.x * blockDim.x + threadIdx.x;
  if (i < n) b[i] = a[i];
}

// perm[q] = position of slot q within its destination's CSR segment
__global__ void k_fill_e(const int* __restrict__ rel_e, int* __restrict__ cursor,
                         int* __restrict__ perm, int M2) {
  int q = blockIdx.x * blockDim.x + threadIdx.x;
  if (q >= M2) return;
  perm[q] = atomicAdd(&cursor[rel_e[q]], 1);
}

// ------- mu0 = MLP_u(0), me0 = MLP_e(0); also g(layer0) = br for all graphs ----
__global__ void k_mlp0(const float* __restrict__ b1u, const float* __restrict__ W2u,
                       const float* __restrict__ b2u,
                       const float* __restrict__ b1e, const float* __restrict__ W2e,
                       const float* __restrict__ b2e,
                       const float* __restrict__ br,
                       float* __restrict__ mu0, float* __restrict__ me0,
                       float* __restrict__ g, int gn) {
  __shared__ float hu[64], he[128];
  int t = threadIdx.x;                     // 128 threads
  if (t < 64) hu[t] = fmaxf(b1u[t], 0.f);
  he[t] = fmaxf(b1e[t], 0.f);
  __syncthreads();
  if (t < 64) {
    float a = b2u[t];
    for (int k = 0; k < 64; ++k) a = fmaf(hu[k], W2u[k * 64 + t], a);
    mu0[t] = a;
  }
  float a = b2e[t];
  for (int k = 0; k < 128; ++k) a = fmaf(he[k], W2e[k * TWO_E + t], a);
  me0[t] = a;
  if (t < 64) {
    float b = br[t];
    for (int gi = 0; gi < gn; ++gi) g[gi * 64 + t] = b;
  }
}

// ------- layer-0 agg from counts ----------
__global__ void k_agg0(const int* __restrict__ cnt_u, const int* __restrict__ cpos0,
                       const int* __restrict__ cpos1, const float* __restrict__ mu0,
                       const float* __restrict__ me0, float* __restrict__ agg, int nn) {
  int i = blockIdx.x * blockDim.x + threadIdx.x;   // (n, j4)
  int n = i >> 4, j4 = i & 15;
  if (n >= nn) return;
  float cu = (float)cnt_u[n], c0 = (float)cpos0[n], c1 = (float)cpos1[n];
  float4 m = ((const float4*)mu0)[j4];
  float4 a = ((const float4*)me0)[j4];
  float4 b = ((const float4*)(me0 + 64))[j4];
  ((float4*)agg)[i] = make_float4(cu * m.x + c0 * a.x + c1 * b.x,
                                  cu * m.y + c0 * a.y + c1 * b.y,
                                  cu * m.z + c0 * a.z + c1 * b.z,
                                  cu * m.w + c0 * a.w + c1 * b.w);
}

// ---------------- Pab[n] = [h[n]@W1_top + b1 | h[n]@W1_bot] ----------------
// lane = node, wave wq owns 64-col output chunk (round-8 proven structure).
__global__ void __launch_bounds__(256) k_pab(
    const float* __restrict__ h, const float* __restrict__ W1,  // [128][128]
    const float* __restrict__ b1, float* __restrict__ Pab, int nn)
{
  const int lane = threadIdx.x & 63;
  const int wq = __builtin_amdgcn_readfirstlane(threadIdx.x >> 6);  // 0..3
  const int c0 = wq * 64;
  const int rbase = (c0 < 128) ? 0 : 64;
  const int cw = (c0 < 128) ? c0 : (c0 - 128);
  const int node = blockIdx.x * 64 + lane;
  const bool valid = (node < nn);
  const int nc = valid ? node : (nn - 1);
  const float4* h4 = (const float4*)(h + (size_t)nc * E);

  float out[64];
  #pragma unroll
  for (int j = 0; j < 64; ++j) out[j] = 0.f;

  const float* w = W1 + rbase * TWO_E + cw;      // wave-uniform, row stride 128
  for (int k4 = 0; k4 < 16; ++k4) {
    float4 hv = h4[k4];
    #pragma unroll
    for (int u = 0; u < 4; ++u) {
      float hk = (u == 0) ? hv.x : (u == 1) ? hv.y : (u == 2) ? hv.z : hv.w;
      #pragma unroll
      for (int j = 0; j < 64; ++j) out[j] = fmaf(hk, w[j], out[j]);
      w += TWO_E;
    }
  }
  if (c0 < 128) {
    #pragma unroll
    for (int j = 0; j < 64; ++j) out[j] += b1[cw + j];
  }
  if (valid) {
    float4* op = (float4*)(Pab + (size_t)node * 256 + c0);
    #pragma unroll
    for (int i = 0; i < 16; ++i)
      op[i] = make_float4(out[4*i], out[4*i+1], out[4*i+2], out[4*i+3]);
  }
}

// -------- edge messages, PAB mode; writes at CSR-permuted positions --------
__global__ void __launch_bounds__(256) k_edge_pab(
    const int* __restrict__ rel_e, const int* __restrict__ perm,
    const float* __restrict__ Pab,
    const float* __restrict__ W2, const float* __restrict__ b2,
    float* __restrict__ msgbuf, int me)
{
  __shared__ __align__(16) float tl[64 * 132];
  const int tid = threadIdx.x;
  const int lane = tid & 63;
  const int wq = __builtin_amdgcn_readfirstlane(tid >> 6);
  const int e = blockIdx.x * 64 + lane;
  const bool valid = (e < me);
  const int ec = valid ? e : (me - 1);
  const int2 sd = ((const int2*)rel_e)[ec];
  const int2 pp = ((const int2*)perm)[ec];       // CSR positions for (->s, ->d)
  const int s = sd.x, d = sd.y;

  {
    const float4* pa = (const float4*)(Pab + (size_t)s * 256 + wq * 32);
    const float4* pb = (const float4*)(Pab + (size_t)d * 256 + 128 + wq * 32);
    float4* trow = (float4*)&tl[lane * 132 + wq * 32];
    #pragma unroll
    for (int i = 0; i < 8; ++i) {
      float4 va = pa[i], vb = pb[i];
      trow[i] = make_float4(fmaxf(va.x + vb.x, 0.f), fmaxf(va.y + vb.y, 0.f),
                            fmaxf(va.z + vb.z, 0.f), fmaxf(va.w + vb.w, 0.f));
    }
  }
  __syncthreads();

  float o[32];
  {
    const float* bp = b2 + wq * 32;
    #pragma unroll
    for (int i = 0; i < 32; ++i) o[i] = bp[i];
  }
  {
    const float4* tr = (const float4*)&tl[lane * 132];
    const float* w = W2 + wq * 32;
    #pragma unroll 4
    for (int kk = 0; kk < 32; ++kk) {
      float4 tv = tr[kk];
      sfma32(o, tv.x, w);
      sfma32(o, tv.y, w + TWO_E);
      sfma32(o, tv.z, w + 2 * TWO_E);
      sfma32(o, tv.w, w + 3 * TWO_E);
      w += 4 * TWO_E;
    }
  }
  if (valid) {
    int p0 = (wq >> 1) ? pp.y : pp.x;            // out 0:64 -> s-slot, 64:128 -> d-slot
    float4* mp = (float4*)(msgbuf + (size_t)p0 * E + (wq & 1) * 32);
    #pragma unroll
    for (int i = 0; i < 8; ++i)
      mp[i] = make_float4(o[4*i], o[4*i+1], o[4*i+2], o[4*i+3]);
  }
}

// -------- edge messages, fallback (reads h; used only if ws too small) ------
__global__ void __launch_bounds__(256) k_edge_fb(
    const int* __restrict__ rel_e, const int* __restrict__ perm,
    const float* __restrict__ h,
    const float* __restrict__ W1, const float* __restrict__ b1,
    const float* __restrict__ W2, const float* __restrict__ b2,
    float* __restrict__ msgbuf, int me)
{
  __shared__ __align__(16) float tl[64 * 132];
  const int tid = threadIdx.x;
  const int lane = tid & 63;
  const int wq = __builtin_amdgcn_readfirstlane(tid >> 6);
  const int e = blockIdx.x * 64 + lane;
  const bool valid = (e < me);
  const int ec = valid ? e : (me - 1);
  const int2 sd = ((const int2*)rel_e)[ec];
  const int2 pp = ((const int2*)perm)[ec];
  const int s = sd.x, d = sd.y;
  const float4* xs4 = (const float4*)(h + (size_t)s * E);
  const float4* xd4 = (const float4*)(h + (size_t)d * E);

  float acc[32];
  {
    const float* bp = b1 + wq * 32;
    #pragma unroll
    for (int i = 0; i < 32; ++i) acc[i] = bp[i];
  }
  {
    const float* w = W1 + wq * 32;
    #pragma unroll 2
    for (int k4 = 0; k4 < 16; ++k4) {
      float4 xv = xs4[k4];
      sfma32(acc, xv.x, w);
      sfma32(acc, xv.y, w + TWO_E);
      sfma32(acc, xv.z, w + 2 * TWO_E);
      sfma32(acc, xv.w, w + 3 * TWO_E);
      w += 4 * TWO_E;
    }
    #pragma unroll 2
    for (int k4 = 0; k4 < 16; ++k4) {
      float4 xv = xd4[k4];
      sfma32(acc, xv.x, w);
      sfma32(acc, xv.y, w + TWO_E);
      sfma32(acc, xv.z, w + 2 * TWO_E);
      sfma32(acc, xv.w, w + 3 * TWO_E);
      w += 4 * TWO_E;
    }
  }
  {
    float4* trow = (float4*)&tl[lane * 132 + wq * 32];
    #pragma unroll
    for (int i = 0; i < 8; ++i)
      trow[i] = make_float4(fmaxf(acc[4*i], 0.f), fmaxf(acc[4*i+1], 0.f),
                            fmaxf(acc[4*i+2], 0.f), fmaxf(acc[4*i+3], 0.f));
  }
  __syncthreads();

  float o[32];
  {
    const float* bp = b2 + wq * 32;
    #pragma unroll
    for (int i = 0; i < 32; ++i) o[i] = bp[i];
  }
  {
    const float4* tr = (const float4*)&tl[lane * 132];
    const float* w = W2 + wq * 32;
    #pragma unroll 4
    for (int kk = 0; kk < 32; ++kk) {
      float4 tv = tr[kk];
      sfma32(o, tv.x, w);
      sfma32(o, tv.y, w + TWO_E);
      sfma32(o, tv.z, w + 2 * TWO_E);
      sfma32(o, tv.w, w + 3 * TWO_E);
      w += 4 * TWO_E;
    }
  }
  if (valid) {
    int p0 = (wq >> 1) ? pp.y : pp.x;
    float4* mp = (float4*)(msgbuf + (size_t)p0 * E + (wq & 1) * 32);
    #pragma unroll
    for (int i = 0; i < 8; ++i)
      mp[i] = make_float4(o[4*i], o[4*i+1], o[4*i+2], o[4*i+3]);
  }
}

// ------- gather: agg[n] += streaming sum of msgbuf[startp[n]..startp[n+1]) ----
__global__ void __launch_bounds__(256) k_gather(
    const float* __restrict__ msgbuf, const int* __restrict__ startp,
    float* __restrict__ agg, int nn)
{
  int wave = threadIdx.x >> 6;
  int j = threadIdx.x & 63;
  int n = blockIdx.x * 4 + wave;
  if (n >= nn) return;
  int s0 = startp[n], s1 = startp[n + 1];
  int cnt = s1 - s0;
  const float* p = msgbuf + (size_t)s0 * E + j;
  float v0 = 0.f, v1 = 0.f;
  int i = 0;
  for (; i + 1 < cnt; i += 2) { v0 += p[0]; v1 += p[E]; p += 2 * E; }
  if (i < cnt) v0 += p[0];
  agg[(size_t)n * E + j] += v0 + v1;
}

// ------- fused readout+proj: one block per graph (contiguous node runs) ----
__global__ void __launch_bounds__(256) k_readout_g(
    const float* __restrict__ h, const int* __restrict__ gids,
    const float* __restrict__ Wr, const float* __restrict__ br,
    float* __restrict__ g, int nn, int npg)
{
  __shared__ float ls[4][64];
  __shared__ float grow[64];
  const int j = threadIdx.x & 63;
  const int w = threadIdx.x >> 6;
  const int base = blockIdx.x * npg;
  float acc = 0.f;
  for (int i = w; i < npg; i += 4) {
    int node = base + i;
    if (node < nn) acc += h[(size_t)node * 64 + j];
  }
  ls[w][j] = acc;
  __syncthreads();
  if (w == 0) grow[j] = ls[0][j] + ls[1][j] + ls[2][j] + ls[3][j];
  __syncthreads();
  float p = 0.f;
  #pragma unroll
  for (int kk = 0; kk < 16; ++kk) {
    int k = w * 16 + kk;
    p = fmaf(grow[k], Wr[k * 64 + j], p);
  }
  ls[w][j] = p;
  __syncthreads();
  if (w == 0) {
    int gout = gids[base];
    g[gout * 64 + j] = ls[0][j] + ls[1][j] + ls[2][j] + ls[3][j] + br[j];
  }
}

// -------- node update: h[n] += LN(MLPu([h,agg])) + LN(MLPg([h,g[gid]]))
// DO_UMSG: afterwards stage h_new in LDS and compute next layer's unary
// message: agg[n] = cnt_u[n] * MLP_u(h_new[n]).
template <bool DO_UMSG>
__global__ void __launch_bounds__(256) k_update(
    float* __restrict__ h, float* __restrict__ agg,
    const float* __restrict__ gvec, const int* __restrict__ gids,
    const float* __restrict__ Wu1, const float* __restrict__ bu1,
    const float* __restrict__ Wu2, const float* __restrict__ bu2,
    const float* __restrict__ Wg1, const float* __restrict__ bg1,
    const float* __restrict__ Wg2, const float* __restrict__ bg2,
    const float* __restrict__ lnw, const float* __restrict__ lnb,
    const int* __restrict__ cnt_u,
    const float* __restrict__ Wmu1, const float* __restrict__ bmu1,
    const float* __restrict__ Wmu2, const float* __restrict__ bmu2,
    int nn)
{
  __shared__ __align__(16) float tl[128 * 68];
  __shared__ float st[128 * 5];
  const int tid = threadIdx.x;
  const int lane = tid & 63;
  const int wq = __builtin_amdgcn_readfirstlane(tid >> 6);
  const int g = wq >> 1, q = wq & 1;
  const int n = blockIdx.x * 128 + g * 64 + lane;
  const bool valid = (n < nn);
  const int ncl = valid ? n : (nn - 1);
  const int gid = gids[ncl];
  const float4* hx = (const float4*)(h + (size_t)ncl * E);
  const float4* ax = (const float4*)(agg + (size_t)ncl * E);
  const float4* gx = (const float4*)(gvec + (size_t)gid * E);
  const int nl = g * 64 + lane;

  float res[32];

  #pragma unroll
  for (int pass = 0; pass < 2; ++pass) {
    const float* W1 = (pass == 0) ? Wu1 : Wg1;
    const float* B1 = (pass == 0) ? bu1 : bg1;
    const float* W2 = (pass == 0) ? Wu2 : Wg2;
    const float* B2 = (pass == 0) ? bu2 : bg2;
    const float4* xb = (pass == 0) ? ax : gx;

    float acc[32];
    {
      const float* bp = B1 + q * 32;
      #pragma unroll
      for (int i = 0; i < 32; ++i) acc[i] = bp[i];
    }
    {
      const float* w = W1 + q * 32;
      #pragma unroll 2
      for (int k4 = 0; k4 < 16; ++k4) {
        float4 xv = hx[k4];
        sfma32(acc, xv.x, w);
        sfma32(acc, xv.y, w + E);
        sfma32(acc, xv.z, w + 2 * E);
        sfma32(acc, xv.w, w + 3 * E);
        w += 4 * E;
      }
      #pragma unroll 2
      for (int k4 = 0; k4 < 16; ++k4) {
        float4 xv = xb[k4];
        sfma32(acc, xv.x, w);
        sfma32(acc, xv.y, w + E);
        sfma32(acc, xv.z, w + 2 * E);
        sfma32(acc, xv.w, w + 3 * E);
        w += 4 * E;
      }
    }
    __syncthreads();
    {
      float4* trow = (float4*)&tl[nl * 68 + q * 32];
      #pragma unroll
      for (int i = 0; i < 8; ++i)
        trow[i] = make_float4(fmaxf(acc[4*i], 0.f), fmaxf(acc[4*i+1], 0.f),
                              fmaxf(acc[4*i+2], 0.f), fmaxf(acc[4*i+3], 0.f));
    }
    __syncthreads();

    float o[32];
    {
      const float* bp = B2 + q * 32;
      #pragma unroll
      for (int i = 0; i < 32; ++i) o[i] = bp[i];
    }
    {
      const float4* tr = (const float4*)&tl[nl * 68];
      const float* w = W2 + q * 32;
      #pragma unroll 4
      for (int kk = 0; kk < 16; ++kk) {
        float4 tv = tr[kk];
        sfma32(o, tv.x, w);
        sfma32(o, tv.y, w + E);
        sfma32(o, tv.z, w + 2 * E);
        sfma32(o, tv.w, w + 3 * E);
        w += 4 * E;
      }
    }

    float s1 = 0.f;
    #pragma unroll
    for (int i = 0; i < 32; ++i) s1 += o[i];
    st[nl * 5 + q] = s1;
    __syncthreads();
    float mu = (st[nl * 5 + 0] + st[nl * 5 + 1]) * (1.f / E);
    float s2 = 0.f;
    #pragma unroll
    for (int i = 0; i < 32; ++i) { float dm = o[i] - mu; s2 += dm * dm; }
    st[nl * 5 + 2 + q] = s2;
    __syncthreads();
    float var = (st[nl * 5 + 2] + st[nl * 5 + 3]) * (1.f / E);
    float rs = rsqrtf(var + 1e-5f);
    {
      const float* lw = lnw + q * 32;
      const float* lb = lnb + q * 32;
      #pragma unroll
      for (int i = 0; i < 32; ++i) {
        float v = (o[i] - mu) * rs * lw[i] + lb[i];
        if (pass == 0) res[i] = v; else res[i] += v;
      }
    }
  }

  // ---- residual: h_new = h + res ----
  float hnew[32];
  {
    const float4* hr = (const float4*)(h + (size_t)ncl * E + q * 32);
    #pragma unroll
    for (int i = 0; i < 8; ++i) {
      float4 hv = hr[i];
      hnew[4*i+0] = hv.x + res[4*i+0];
      hnew[4*i+1] = hv.y + res[4*i+1];
      hnew[4*i+2] = hv.z + res[4*i+2];
      hnew[4*i+3] = hv.w + res[4*i+3];
    }
  }
  if (valid) {
    float4* hw = (float4*)(h + (size_t)n * E + q * 32);
    #pragma unroll
    for (int i = 0; i < 8; ++i)
      hw[i] = make_float4(hnew[4*i], hnew[4*i+1], hnew[4*i+2], hnew[4*i+3]);
  }

  if (DO_UMSG) {
    // stage h_new row in LDS (last pass's barriers guarantee tl is free)
    {
      float4* trow = (float4*)&tl[nl * 68 + q * 32];
      #pragma unroll
      for (int i = 0; i < 8; ++i)
        trow[i] = make_float4(hnew[4*i], hnew[4*i+1], hnew[4*i+2], hnew[4*i+3]);
    }
    __syncthreads();

    // unary layer 1: hidden half q over full 64-wide h_new
    float acc[32];
    {
      const float* bp = bmu1 + q * 32;
      #pragma unroll
      for (int i = 0; i < 32; ++i) acc[i] = bp[i];
    }
    {
      const float4* tr = (const float4*)&tl[nl * 68];
      const float* w = Wmu1 + q * 32;
      #pragma unroll 4
      for (int kk = 0; kk < 16; ++kk) {
        float4 tv = tr[kk];
        sfma32(acc, tv.x, w);
        sfma32(acc, tv.y, w + E);
        sfma32(acc, tv.z, w + 2 * E);
        sfma32(acc, tv.w, w + 3 * E);
        w += 4 * E;
      }
    }
    __syncthreads();        // all reads of h_new done before overwrite
    {
      float4* trow = (float4*)&tl[nl * 68 + q * 32];
      #pragma unroll
      for (int i = 0; i < 8; ++i)
        trow[i] = make_float4(fmaxf(acc[4*i], 0.f), fmaxf(acc[4*i+1], 0.f),
                              fmaxf(acc[4*i+2], 0.f), fmaxf(acc[4*i+3], 0.f));
    }
    __syncthreads();

    // unary layer 2: output chunk q over all 64 hidden; agg = cf * msg
    float o[32];
    {
      const float* bp = bmu2 + q * 32;
      #pragma unroll
      for (int i = 0; i < 32; ++i) o[i] = bp[i];
    }
    {
      const float4* tr = (const float4*)&tl[nl * 68];
      const float* w = Wmu2 + q * 32;
      #pragma unroll 4
      for (int kk = 0; kk < 16; ++kk) {
        float4 tv = tr[kk];
        sfma32(o, tv.x, w);
        sfma32(o, tv.y, w + E);
        sfma32(o, tv.z, w + 2 * E);
        sfma32(o, tv.w, w + 3 * E);
        w += 4 * E;
      }
    }
    if (valid) {
      float cf = (float)cnt_u[n];
      float4* ap = (float4*)(agg + (size_t)n * E + q * 32);
      #pragma unroll
      for (int i = 0; i < 8; ++i)
        ap[i] = make_float4(o[4*i] * cf, o[4*i+1] * cf, o[4*i+2] * cf, o[4*i+3] * cf);
    }
  }
}

extern "C" void kernel_launch(void* const* d_in, const int* in_sizes, int n_in,
                              void* d_out, int out_size, void* d_ws, size_t ws_size,
                              hipStream_t stream) {
  (void)n_in; (void)out_size;
  const int*   rel_u = (const int*)d_in[0];
  const int*   rel_e = (const int*)d_in[1];
  const int*   gids  = (const int*)d_in[2];
  const float* Wm1_u = (const float*)d_in[4];
  const float* bm1_u = (const float*)d_in[5];
  const float* Wm2_u = (const float*)d_in[6];
  const float* bm2_u = (const float*)d_in[7];
  const float* Wm1_e = (const float*)d_in[8];
  const float* bm1_e = (const float*)d_in[9];
  const float* Wm2_e = (const float*)d_in[10];
  const float* bm2_e = (const float*)d_in[11];
  const float* Wu1   = (const float*)d_in[12];
  const float* bu1   = (const float*)d_in[13];
  const float* Wu2   = (const float*)d_in[14];
  const float* bu2   = (const float*)d_in[15];
  const float* lnw   = (const float*)d_in[16];
  const float* lnb   = (const float*)d_in[17];
  const float* Wr    = (const float*)d_in[18];
  const float* br    = (const float*)d_in[19];
  const float* Wg1   = (const float*)d_in[20];
  const float* bg1   = (const float*)d_in[21];
  const float* Wg2   = (const float*)d_in[22];
  const float* bg2   = (const float*)d_in[23];

  const int MU_ = in_sizes[0];          // 100000
  const int ME_ = in_sizes[1] / 2;      // 200000
  const int NN  = in_sizes[2];          // 50000
  const int GN  = 100;
  const int NPG = NN / GN;              // 500 nodes per graph (contiguous)
  const int M2  = 2 * ME_;              // 400000 edge message slots

  // ---- workspace layout ----
  float* h      = (float*)d_out;
  float* agg    = (float*)d_ws;                            // [N*64]
  float* g      = agg + (size_t)NN * E;                    // [G*64]
  float* mu0    = g + (size_t)GN * E;                      // [64]
  float* me0    = mu0 + 64;                                // [128]
  float* msgbuf = me0 + TWO_E;                             // [M2*64]
  int*   cnt    = (int*)(msgbuf + (size_t)M2 * E);         // [N]
  int*   startp = cnt + NN;                                // [N+1]
  int*   cursor = startp + NN + 1;                         // [N]
  int*   cnt_u  = cursor + NN;                             // [N]
  int*   cpos0  = cnt_u + NN;                              // [N]
  int*   cpos1  = cpos0 + NN;                              // [N]
  int*   perm   = cpos1 + NN;                              // [M2]
  size_t int_end = (size_t)(perm + M2 - (int*)d_ws);
  size_t pab_off = (int_end + 3) & ~(size_t)3;
  float* Pab    = (float*)d_ws + pab_off;                  // [N*256]
  size_t need_pab = (pab_off + (size_t)NN * 256) * 4;
  const bool pab_mode = (ws_size >= need_pab);

  { // h = 0
    int n4 = NN * E / 4;
    k_zero<<<(n4 + 255) / 256, 256, 0, stream>>>((float4*)h, n4);
  }
  { // zero int region cnt..cpos1 (6N+1 ints; spill into perm[0..2] is ok)
    int n4 = (6 * NN + 4) / 4;
    k_zero<<<(n4 + 255) / 256, 256, 0, stream>>>((float4*)cnt, n4);
  }
  // ---- CSR + counts + constant messages (once; graph static) ----
  k_count_e<<<(M2 + 255) / 256, 256, 0, stream>>>(rel_e, cnt, cpos0, cpos1, M2);
  k_count_u<<<(MU_ + 255) / 256, 256, 0, stream>>>(rel_u, cnt_u, MU_);
  k_scan<<<1, 1024, 0, stream>>>(cnt, startp, NN, M2);
  k_copyint<<<(NN + 255) / 256, 256, 0, stream>>>(startp, cursor, NN);
  k_fill_e<<<(M2 + 255) / 256, 256, 0, stream>>>(rel_e, cursor, perm, M2);
  k_mlp0<<<1, 128, 0, stream>>>(bm1_u, Wm2_u, bm2_u, bm1_e, Wm2_e, bm2_e,
                                br, mu0, me0, g, GN);

  // ---- layer 0: messages constant; g = br; update also emits layer-1 unary agg
  k_agg0<<<(NN * 16 + 255) / 256, 256, 0, stream>>>(cnt_u, cpos0, cpos1, mu0, me0, agg, NN);
  k_update<true><<<(NN + 127) / 128, 256, 0, stream>>>(
      h, agg, g, gids, Wu1, bu1, Wu2, bu2, Wg1, bg1, Wg2, bg2, lnw, lnb,
      cnt_u, Wm1_u, bm1_u, Wm2_u, bm2_u, NN);

  // ---- layers 1..3 ----
  for (int l = 1; l < 4; ++l) {
    if (pab_mode) {
      k_pab<<<(NN + 63) / 64, 256, 0, stream>>>(h, Wm1_e, bm1_e, Pab, NN);
      k_edge_pab<<<(ME_ + 63) / 64, 256, 0, stream>>>(
          rel_e, perm, Pab, Wm2_e, bm2_e, msgbuf, ME_);
    } else {
      k_edge_fb<<<(ME_ + 63) / 64, 256, 0, stream>>>(
          rel_e, perm, h, Wm1_e, bm1_e, Wm2_e, bm2_e, msgbuf, ME_);
    }
    k_gather<<<(NN + 3) / 4, 256, 0, stream>>>(msgbuf, startp, agg, NN);
    k_readout_g<<<GN, 256, 0, stream>>>(h, gids, Wr, br, g, NN, NPG);
    if (l < 3)
      k_update<true><<<(NN + 127) / 128, 256, 0, stream>>>(
          h, agg, g, gids, Wu1, bu1, Wu2, bu2, Wg1, bg1, Wg2, bg2, lnw, lnb,
          cnt_u, Wm1_u, bm1_u, Wm2_u, bm2_u, NN);
    else
      k_update<false><<<(NN + 127) / 128, 256, 0, stream>>>(
          h, agg, g, gids, Wu1, bu1, Wu2, bu2, Wg1, bg1, Wg2, bg2, lnw, lnb,
          cnt_u, Wm1_u, bm1_u, Wm2_u, bm2_u, NN);
  }
}